// Round 1
// 409.736 us; speedup vs baseline: 1.1526x; 1.1526x over previous
//
#include <hip/hip_runtime.h>
#include <hip/hip_bf16.h>
#include <math.h>

#define SEQ   2048
#define EMBED 2048
#define NHEAD 16
#define DHEAD 128
#define BATCH 2

#define NX   ((size_t)BATCH * SEQ * EMBED)   // 8388608
#define NW1  ((size_t)3 * EMBED * EMBED)     // 12582912
#define NB1  ((size_t)3 * EMBED)             // 6144
#define NW2  ((size_t)EMBED * EMBED)         // 4194304
#define NB2  ((size_t)EMBED)                 // 2048

typedef __bf16 bf16;
typedef __attribute__((__ext_vector_type__(8))) __bf16 bf16x8;
typedef __attribute__((__ext_vector_type__(4))) __bf16 bf16x4;
typedef __attribute__((__ext_vector_type__(4))) float f32x4;
typedef __attribute__((__ext_vector_type__(4))) unsigned int u32x4;

#define NEG_BIG (-1.0e30f)

__device__ __forceinline__ f32x4 mfma_16x16x32(bf16x8 a, bf16x8 b, f32x4 c) {
  return __builtin_amdgcn_mfma_f32_16x16x32_bf16(a, b, c, 0, 0, 0);
}

// async global->LDS, 16B per lane; dst is wave-uniform base, lane i lands at
// dst + i*16B (m97-verified pattern)
__device__ __forceinline__ void llds16(bf16* dst, const bf16* src) {
  __builtin_amdgcn_global_load_lds(
      (const __attribute__((address_space(1))) void*)src,
      (__attribute__((address_space(3))) void*)dst, 16, 0, 0);
}

// ---------------------------------------------------------------------------
// Input normalization: detect fp32 vs bf16 storage, convert to bf16 ws.
// ---------------------------------------------------------------------------
__global__ void convert_inputs(const void* __restrict__ xin,
                               const void* __restrict__ w1in,
                               const void* __restrict__ b1in,
                               const void* __restrict__ w2in,
                               const void* __restrict__ b2in,
                               bf16* __restrict__ xb, bf16* __restrict__ w1b,
                               bf16* __restrict__ b1b, bf16* __restrict__ w2b,
                               bf16* __restrict__ b2b, int* __restrict__ flagp)
{
  __shared__ int sflag;
  if (threadIdx.x == 0) sflag = 0;
  __syncthreads();
  const unsigned short* xh = (const unsigned short*)xin;
  int huge = 0;
  for (int i = threadIdx.x; i < 2048; i += 256) {
    float f = __uint_as_float((unsigned int)xh[i] << 16);
    if (!(fabsf(f) <= 1e4f)) huge = 1;  // catches NaN/Inf too
  }
  if (huge) sflag = 1;
  __syncthreads();
  const int isf32 = sflag;
  if (blockIdx.x == 0 && threadIdx.x == 0) *flagp = isf32;

  const void* srcs[5] = {xin, w1in, b1in, w2in, b2in};
  bf16* dsts[5] = {xb, w1b, b1b, w2b, b2b};
  const size_t lens[5] = {NX, NW1, NB1, NW2, NB2};
  const size_t gid = (size_t)blockIdx.x * blockDim.x + threadIdx.x;
  const size_t gstride = (size_t)gridDim.x * blockDim.x;
  for (int sidx = 0; sidx < 5; ++sidx) {
    const size_t n8 = lens[sidx] >> 3;
    bf16* d = dsts[sidx];
    if (isf32) {
      const float* s = (const float*)srcs[sidx];
      for (size_t i = gid; i < n8; i += gstride) {
        const float* sp = s + i * 8;
        bf16x8 r;
#pragma unroll
        for (int j = 0; j < 8; ++j) r[j] = (bf16)sp[j];
        *(bf16x8*)(d + i * 8) = r;
      }
    } else {
      const u32x4* s = (const u32x4*)srcs[sidx];
      for (size_t i = gid; i < n8; i += gstride)
        *(u32x4*)(d + i * 8) = s[i];
    }
  }
}

// ---------------------------------------------------------------------------
// NT GEMM: C[M,N] = A[M,K] * B[N,K]^T + bias[N]  (bf16 in, fp32 acc)
// m97 structure: 128x128 tile, BK=32, global_load_lds width-16 staging.
// launch_bounds(256,4): 4 blocks/CU resident (VGPR ~120 unified, cap 128).
// MODE 0: QKV epilogue -> q [BH,S,Dh], k [BH,S,Dh], v^T [BH,Dh,S]
// MODE 1: plain epilogue -> out[M, 2048], dtype per *flagp
// ---------------------------------------------------------------------------
template <int MODE>
__global__ __launch_bounds__(256, 4) void gemm_nt(
    const bf16* __restrict__ A, const bf16* __restrict__ B,
    const bf16* __restrict__ bias, int K,
    void* __restrict__ out0v, bf16* __restrict__ out1, bf16* __restrict__ out2,
    const int* __restrict__ flagp)
{
  __shared__ bf16 sA[128 * 32];
  __shared__ bf16 sB[128 * 32];
  const int t = threadIdx.x;
  const int lane = t & 63, w = t >> 6;
  const int wm = w >> 1, wn = w & 1;
  const int lr = lane & 15, lq = lane >> 4;
  const int m0 = blockIdx.y * 128, n0 = blockIdx.x * 128;

  f32x4 acc[4][4];
#pragma unroll
  for (int i = 0; i < 4; ++i)
#pragma unroll
    for (int j = 0; j < 4; ++j) acc[i][j] = (f32x4){0.f, 0.f, 0.f, 0.f};

  const bf16* Abase = A + (size_t)m0 * K;
  const bf16* Bbase = B + (size_t)n0 * K;
  const int nK = K >> 5;
  for (int kk = 0; kk < nK; ++kk) {
    const int k0 = kk << 5;
    __syncthreads();  // prior iteration's LDS reads complete
#pragma unroll
    for (int i = 0; i < 2; ++i) {
      const int c = i * 256 + t;
      const int ldsbase = (i * 256 + (t & ~63)) << 3;  // wave-uniform elems
      llds16(sA + ldsbase, Abase + (size_t)(c >> 2) * K + k0 + (c & 3) * 8);
      llds16(sB + ldsbase, Bbase + (size_t)(c >> 2) * K + k0 + (c & 3) * 8);
    }
    __syncthreads();  // vmcnt drain: staging visible

    bf16x8 af[4], bfr[4];
#pragma unroll
    for (int mi = 0; mi < 4; ++mi)
      af[mi] = *(const bf16x8*)(sA + (wm * 64 + mi * 16 + lr) * 32 + lq * 8);
#pragma unroll
    for (int ni = 0; ni < 4; ++ni)
      bfr[ni] = *(const bf16x8*)(sB + (wn * 64 + ni * 16 + lr) * 32 + lq * 8);
#pragma unroll
    for (int mi = 0; mi < 4; ++mi)
#pragma unroll
      for (int ni = 0; ni < 4; ++ni)
        acc[mi][ni] = mfma_16x16x32(af[mi], bfr[ni], acc[mi][ni]);
  }

  // epilogue: C/D layout col = lane&15, row = (lane>>4)*4 + reg
  if (MODE == 0) {
    const int which = n0 >> 11;
    const int h = (n0 >> 7) & 15;
    const int bb = m0 >> 11;
    const int s0 = m0 & 2047;
    if (which == 2) {
      // V transposed: [BH, Dh, S]; 4 regs = 4 consecutive s -> 8B store
      bf16* dst = out2;
#pragma unroll
      for (int ni = 0; ni < 4; ++ni) {
        const int col = wn * 64 + ni * 16 + lr;
        const float bv = (float)bias[n0 + col];
        bf16* rowp = dst + ((size_t)(bb * NHEAD + h) * DHEAD + col) * SEQ + s0;
#pragma unroll
        for (int mi = 0; mi < 4; ++mi) {
          bf16x4 pk;
#pragma unroll
          for (int reg = 0; reg < 4; ++reg)
            pk[reg] = (bf16)(acc[mi][ni][reg] + bv);
          *(bf16x4*)(rowp + wm * 64 + mi * 16 + lq * 4) = pk;
        }
      }
    } else {
      bf16* dst = (which == 0) ? (bf16*)out0v : out1;
#pragma unroll
      for (int ni = 0; ni < 4; ++ni) {
        const int col = wn * 64 + ni * 16 + lr;
        const float bv = (float)bias[n0 + col];
#pragma unroll
        for (int mi = 0; mi < 4; ++mi)
#pragma unroll
          for (int reg = 0; reg < 4; ++reg) {
            const int row = wm * 64 + mi * 16 + lq * 4 + reg;
            const int s = s0 + row;
            dst[((size_t)(bb * NHEAD + h) * SEQ + s) * DHEAD + col] =
                (bf16)(acc[mi][ni][reg] + bv);
          }
      }
    }
  } else {
    const int isf32 = *flagp;
#pragma unroll
    for (int ni = 0; ni < 4; ++ni) {
      const int col = wn * 64 + ni * 16 + lr;
      const float bv = (float)bias[n0 + col];
#pragma unroll
      for (int mi = 0; mi < 4; ++mi)
#pragma unroll
        for (int reg = 0; reg < 4; ++reg) {
          const int row = wm * 64 + mi * 16 + lq * 4 + reg;
          const float v = acc[mi][ni][reg] + bv;
          const size_t idx = (size_t)(m0 + row) * EMBED + n0 + col;
          if (isf32) ((float*)out0v)[idx] = v;
          else       ((bf16*)out0v)[idx] = (bf16)v;
        }
    }
  }
}

// ---------------------------------------------------------------------------
// Causal flash attention, pair-balanced: block (bh, p) handles q-tiles
// {p, 31-p} (64 rows each) over the shared K range kt=0..31-p.
//
// SWAPPED-OPERAND FORM (T12 principle): compute S^T = mfma(K_frag, Q_frag).
// Operand layouts are symmetric, so the same LDS reads feed the swap; the
// C-layout then gives each lane ONE q (= w*16 + lane&15) with 16 k-scores
// in registers. Softmax row-reduce = 15 local ops + 2 shuffles (across the
// 4 lq lanes), m/l are scalars, and P packs into 4x ds_write_b64 into an
// XOR-swizzled [q][64] sP (conflict-free write AND read).
// PV computes O^T = V^T * P^T (A = sV frags, unchanged reads).
// ---------------------------------------------------------------------------
__device__ __forceinline__ void qk_softmax_tile(
    const bf16* __restrict__ sK, bf16* __restrict__ sP, const bf16x8* aq,
    float& m_i, float& l_i, f32x4* oacc, int kt, int qt,
    int w, int lr, int lq, int sPofs)
{
  const float scale = 0.08838834764831845f;  // 1/sqrt(128)
  f32x4 tacc[4];
#pragma unroll
  for (int ni = 0; ni < 4; ++ni) tacc[ni] = (f32x4){0.f, 0.f, 0.f, 0.f};
#pragma unroll
  for (int ks = 0; ks < 4; ++ks)
#pragma unroll
    for (int ni = 0; ni < 4; ++ni) {
      bf16x8 bk = *(const bf16x8*)(sK + (ni * 16 + lr) * 136 + ks * 32 + lq * 8);
      // swapped: A = K-tile rows (k), B = Q rows (q) -> D = S^T[k, q]
      tacc[ni] = mfma_16x16x32(bk, aq[ks], tacc[ni]);
    }
  // lane holds S^T[k = kt*64 + ni*16 + lq*4 + reg][q = qt*64 + w*16 + lr]
  float pp[4][4];
  const int qg = qt * 64 + w * 16 + lr;
#pragma unroll
  for (int ni = 0; ni < 4; ++ni)
#pragma unroll
    for (int reg = 0; reg < 4; ++reg) {
      float sv = tacc[ni][reg] * scale;
      if (kt == qt) {
        const int kg = kt * 64 + ni * 16 + lq * 4 + reg;
        if (kg > qg) sv = NEG_BIG;
      }
      pp[ni][reg] = sv;
    }
  // local max over the lane's 16 scores (tree), then reduce across lq lanes
  float m01, m23, mx;
  {
    float a0 = fmaxf(fmaxf(pp[0][0], pp[0][1]), fmaxf(pp[0][2], pp[0][3]));
    float a1 = fmaxf(fmaxf(pp[1][0], pp[1][1]), fmaxf(pp[1][2], pp[1][3]));
    float a2 = fmaxf(fmaxf(pp[2][0], pp[2][1]), fmaxf(pp[2][2], pp[2][3]));
    float a3 = fmaxf(fmaxf(pp[3][0], pp[3][1]), fmaxf(pp[3][2], pp[3][3]));
    m01 = fmaxf(a0, a1);
    m23 = fmaxf(a2, a3);
    mx = fmaxf(m01, m23);
  }
  mx = fmaxf(mx, __shfl_xor(mx, 16, 64));
  mx = fmaxf(mx, __shfl_xor(mx, 32, 64));
  const float mnew = fmaxf(m_i, mx);
  const float alpha = __expf(m_i - mnew);
  float ls = 0.f;
#pragma unroll
  for (int ni = 0; ni < 4; ++ni) {
    float s0 = __expf(pp[ni][0] - mnew);
    float s1 = __expf(pp[ni][1] - mnew);
    float s2 = __expf(pp[ni][2] - mnew);
    float s3 = __expf(pp[ni][3] - mnew);
    pp[ni][0] = s0; pp[ni][1] = s1; pp[ni][2] = s2; pp[ni][3] = s3;
    ls += (s0 + s1) + (s2 + s3);
  }
  ls += __shfl_xor(ls, 16, 64);
  ls += __shfl_xor(ls, 32, 64);
  l_i = l_i * alpha + ls;
  m_i = mnew;
#pragma unroll
  for (int dt = 0; dt < 8; ++dt) oacc[dt] *= alpha;
  // pack P[q][k] rows: 4 consecutive k per reg -> bf16x4, XOR-swizzled cols
  bf16* rowp = sP + (sPofs + w * 16 + lr) * 64;
  const int swz = lr & 7;
#pragma unroll
  for (int ni = 0; ni < 4; ++ni) {
    bf16x4 pk;
#pragma unroll
    for (int reg = 0; reg < 4; ++reg) pk[reg] = (bf16)pp[ni][reg];
    const int col = ni * 16 + lq * 4;
    const int scol = (((col >> 3) ^ swz) << 3) | (col & 7);
    *(bf16x4*)(rowp + scol) = pk;
  }
}

__device__ __forceinline__ void pv_tile(const bf16* __restrict__ sP,
                                        const bf16* __restrict__ sV,
                                        f32x4* oacc, int w, int lr, int lq,
                                        int sPofs)
{
  const bf16* rowp = sP + (sPofs + w * 16 + lr) * 64;
  const int swz = lr & 7;
#pragma unroll
  for (int ks2 = 0; ks2 < 2; ++ks2) {
    const int chunk = ks2 * 4 + lq;                    // 8-elem chunk of k
    bf16x8 bp = *(const bf16x8*)(rowp + ((chunk ^ swz) << 3));
#pragma unroll
    for (int dt = 0; dt < 8; ++dt) {
      bf16x8 av =
          *(const bf16x8*)(sV + (dt * 16 + lr) * 72 + ks2 * 32 + lq * 8);
      // O^T = V^T * P^T : C row = d (lq*4+reg), col = q (lr)
      oacc[dt] = mfma_16x16x32(av, bp, oacc[dt]);
    }
  }
}

__global__ __launch_bounds__(256, 2) void attn_fwd(
    const bf16* __restrict__ qb, const bf16* __restrict__ kb,
    const bf16* __restrict__ vt, bf16* __restrict__ aout)
{
  __shared__ bf16 sK[64 * 136];    // [k][d], +8 pad
  __shared__ bf16 sV[128 * 72];    // [d][k], +8 pad
  __shared__ bf16 sP[128 * 64];    // [q][k] XOR-swizzled: rows 0-63 lo, 64-127 hi
  const int t = threadIdx.x;
  const int lane = t & 63, w = t >> 6;
  const int lr = lane & 15, lq = lane >> 4;
  const int p  = blockIdx.x & 15;
  const int bh = blockIdx.x >> 4;
  const int bb = bh >> 4, h = bh & 15;
  const int qlo = p, qhi = 31 - p;

  bf16x8 aqL[4], aqH[4];
  {
    const bf16* qpL =
        qb + ((size_t)bh * SEQ + qlo * 64 + w * 16 + lr) * DHEAD + lq * 8;
    const bf16* qpH =
        qb + ((size_t)bh * SEQ + qhi * 64 + w * 16 + lr) * DHEAD + lq * 8;
#pragma unroll
    for (int ks = 0; ks < 4; ++ks) {
      aqL[ks] = *(const bf16x8*)(qpL + ks * 32);
      aqH[ks] = *(const bf16x8*)(qpH + ks * 32);
    }
  }

  f32x4 oL[8], oH[8];
#pragma unroll
  for (int i = 0; i < 8; ++i) {
    oL[i] = (f32x4){0.f, 0.f, 0.f, 0.f};
    oH[i] = (f32x4){0.f, 0.f, 0.f, 0.f};
  }
  float mL = NEG_BIG, mH = NEG_BIG;
  float lL = 0.f, lH = 0.f;

  bf16x8 rk[4], rv[4];
  const int kr_ = t >> 4, kd_ = t & 15;
  const int vr_ = t >> 3, vk_ = t & 7;
#define FETCH(ktv)                                                          \
  {                                                                         \
    const int _kt = (ktv);                                                  \
    _Pragma("unroll") for (int i = 0; i < 4; ++i) {                         \
      rk[i] = *(const bf16x8*)(kb + ((size_t)bh * SEQ + _kt * 64 +          \
                                     (i * 16 + kr_)) * DHEAD + kd_ * 8);    \
      rv[i] = *(const bf16x8*)(vt + ((size_t)bh * DHEAD + (i * 32 + vr_)) * \
                                     SEQ + _kt * 64 + vk_ * 8);             \
    }                                                                       \
  }
#define COMMIT()                                                            \
  {                                                                         \
    _Pragma("unroll") for (int i = 0; i < 4; ++i) {                         \
      *(bf16x8*)(sK + (i * 16 + kr_) * 136 + kd_ * 8) = rk[i];              \
      *(bf16x8*)(sV + (i * 32 + vr_) * 72 + vk_ * 8) = rv[i];               \
    }                                                                       \
  }

  FETCH(0);
  COMMIT();
  __syncthreads();

  for (int kt = 0; kt <= qhi; ++kt) {
    if (kt < qhi) FETCH(kt + 1);
    const bool doLo = (kt <= qlo);

    qk_softmax_tile(sK, sP, aqH, mH, lH, oH, kt, qhi, w, lr, lq, 64);
    if (doLo) qk_softmax_tile(sK, sP, aqL, mL, lL, oL, kt, qlo, w, lr, lq, 0);
    // sP rows are wave-private: wave-level LDS drain suffices
    asm volatile("s_waitcnt lgkmcnt(0)" ::: "memory");
    pv_tile(sP, sV, oH, w, lr, lq, 64);
    if (doLo) pv_tile(sP, sV, oL, w, lr, lq, 0);

    __syncthreads();
    if (kt < qhi) {
      COMMIT();
      __syncthreads();
    }
  }

  // epilogue: lane holds O^T[d = dt*16 + lq*4 + reg][q = qt*64 + w*16 + lr]
#pragma unroll
  for (int side = 0; side < 2; ++side) {
    const f32x4* oacc = side ? oH : oL;
    const float linv = 1.0f / (side ? lH : lL);
    const int qt = side ? qhi : qlo;
    const int qg = qt * 64 + w * 16 + lr;
    bf16* outp = aout + ((size_t)bb * SEQ + qg) * EMBED + h * 128 + lq * 4;
#pragma unroll
    for (int dt = 0; dt < 8; ++dt) {
      bf16x4 pk;
#pragma unroll
      for (int reg = 0; reg < 4; ++reg)
        pk[reg] = (bf16)(oacc[dt][reg] * linv);
      *(bf16x4*)(outp + dt * 16) = pk;
    }
  }
#undef FETCH
#undef COMMIT
}

extern "C" void kernel_launch(void* const* d_in, const int* in_sizes, int n_in,
                              void* d_out, int out_size, void* d_ws, size_t ws_size,
                              hipStream_t stream) {
  const void* x    = d_in[0];
  const void* Wqkv = d_in[1];
  const void* bqkv = d_in[2];
  const void* Wout = d_in[3];
  const void* bout = d_in[4];

  int* flagp = (int*)d_ws;
  bf16* base = (bf16*)((char*)d_ws + 256);
  bf16* xb   = base;
  bf16* w1b  = xb + NX;
  bf16* b1b  = w1b + NW1;
  bf16* w2b  = b1b + NB1;
  bf16* b2b  = w2b + NW2;
  bf16* qb   = b2b + NB2;
  bf16* kb   = qb + NX;
  bf16* vt   = kb + NX;
  bf16* aout = vt + NX;

  dim3 blk(256);
  convert_inputs<<<dim3(1024), blk, 0, stream>>>(
      x, Wqkv, bqkv, Wout, bout, xb, w1b, b1b, w2b, b2b, flagp);
  // QKV projection: M=4096, N=6144, K=2048
  gemm_nt<0><<<dim3(48, 32), blk, 0, stream>>>(xb, w1b, b1b, EMBED,
                                               (void*)qb, kb, vt, flagp);
  // attention: 32 bh * 16 balanced pairs
  attn_fwd<<<dim3(512), blk, 0, stream>>>(qb, kb, vt, aout);
  // out projection: M=4096, N=2048, K=2048
  gemm_nt<1><<<dim3(16, 32), blk, 0, stream>>>(aout, w2b, b2b, EMBED,
                                               d_out, nullptr, nullptr, flagp);
}